// Round 5
// baseline (833.125 us; speedup 1.0000x reference)
//
#include <hip/hip_runtime.h>

#define BN_EPS 1e-4f
#define NREP 8   // stats replica banks (atomic-contention spreading)

typedef _Float16 f16x8 __attribute__((ext_vector_type(8)));
typedef _Float16 f16x4 __attribute__((ext_vector_type(4)));
typedef _Float16 f16x2 __attribute__((ext_vector_type(2)));
typedef float f32x4 __attribute__((ext_vector_type(4)));

// ---------------------------------------------------------------------------
// MFMA rulebook conv, CIN=16, grid-stride persistent form.
// wave = 16 output sites per group; one 16x16x32 f16 MFMA covers 2 taps.
// Sentinel idx==Nin gathers the zero row of A16 -> branchless (HW merges the
// same-address lanes into one line-request).
// __launch_bounds__(256,4): 128-VGPR budget so the 14x16B B-fragment array
// stays register-resident (R4's 60-VGPR build re-fetched B every group:
// ~7M extra line-requests/dispatch).
// BN stats in registers across the group loop; ONE atomic set per block into
// replica bank (blockIdx & 7).
template <int K>
__global__ __launch_bounds__(256, 4) void conv16_k(
    const _Float16* __restrict__ A16,   // [Nin+1, 16] post-BN fp16, zero row at Nin
    const int* __restrict__ nbr,        // [K, Nout], sentinel == Nin
    const _Float16* __restrict__ WB,    // [(K+1)/2][64][8] packed B fragments
    float* __restrict__ out,            // [Nout, 16] fp32
    float* __restrict__ stats_out,      // [NREP][128] (sum | sumsq@64) or nullptr
    int Nout, int addSkip)
{
    constexpr int PAIRS = (K + 1) / 2;
    const int wave = threadIdx.x >> 6, lane = threadIdx.x & 63;
    const int l15 = lane & 15, q = lane >> 4;
    const int h = q & 1;        // cin half (0: cin 0-7, 1: cin 8-15)
    const int th = q >> 1;      // tap-of-pair select

    f16x8 bfr[PAIRS];
#pragma unroll
    for (int p = 0; p < PAIRS; ++p)
        bfr[p] = *(const f16x8*)(WB + ((size_t)p * 64 + lane) * 8);

    const int ngroups = (Nout + 15) >> 4;
    float s = 0.f, ss = 0.f;

    for (int grp = blockIdx.x * 4 + wave; grp < ngroups; grp += gridDim.x * 4) {
        const int base = grp * 16;
        const int site = min(base + l15, Nout - 1);
        f32x4 acc0 = {0.f, 0.f, 0.f, 0.f}, acc1 = {0.f, 0.f, 0.f, 0.f};
#pragma unroll
        for (int p = 0; p < PAIRS; ++p) {
            const int t = 2 * p + ((2 * p + 1 < K) ? th : 0);  // odd-K: dup last tap
            const int idx = nbr[(size_t)t * Nout + site];
            const f16x8 a = *(const f16x8*)(A16 + (size_t)idx * 16 + h * 8);
            if (p & 1) acc1 = __builtin_amdgcn_mfma_f32_16x16x32_f16(a, bfr[p], acc1, 0, 0, 0);
            else       acc0 = __builtin_amdgcn_mfma_f32_16x16x32_f16(a, bfr[p], acc0, 0, 0, 0);
        }
#pragma unroll
        for (int r = 0; r < 4; ++r) {
            const int row = base + q * 4 + r;
            float v = acc0[r] + acc1[r];
            if (row < Nout) {
                float* op = out + (size_t)row * 16 + l15;
                if (addSkip) v += *op;
                *op = v;
                s += v; ss += v * v;
            }
        }
    }

    if (stats_out) {  // uniform branch (kernel arg)
        s  += __shfl_xor(s, 16);  s  += __shfl_xor(s, 32);
        ss += __shfl_xor(ss, 16); ss += __shfl_xor(ss, 32);
        __shared__ float red[4][32];
        if (lane < 16) { red[wave][l15] = s; red[wave][16 + l15] = ss; }
        __syncthreads();
        if (threadIdx.x < 32) {
            const int t2 = threadIdx.x;
            float* bank = stats_out + (blockIdx.x & (NREP - 1)) * 128;
            atomicAdd(bank + (t2 < 16 ? t2 : 48 + t2),
                      red[0][t2] + red[1][t2] + red[2][t2] + red[3][t2]);
        }
    }
}

// ---------------------------------------------------------------------------
// p1 conv (CIN=2), grid-stride: K-packing k = tap*2 + cin, 2 MFMAs per group.
__global__ __launch_bounds__(256, 4) void convp1_k(
    const _Float16* __restrict__ F16,   // [N0+1, 2], zero row at N0
    const int* __restrict__ nbr,        // [27, N0]
    const _Float16* __restrict__ WB,    // [2][64][8]
    float* __restrict__ out, float* __restrict__ stats_out, int Nout)
{
    const int wave = threadIdx.x >> 6, lane = threadIdx.x & 63;
    const int l15 = lane & 15, q = lane >> 4;

    f16x8 b0 = *(const f16x8*)(WB + (size_t)lane * 8);
    f16x8 b1 = *(const f16x8*)(WB + ((size_t)64 + lane) * 8);

    const int ngroups = (Nout + 15) >> 4;
    float s = 0.f, ss = 0.f;

    for (int grp = blockIdx.x * 4 + wave; grp < ngroups; grp += gridDim.x * 4) {
        const int base = grp * 16;
        const int site = min(base + l15, Nout - 1);
        f32x4 acc = {0.f, 0.f, 0.f, 0.f};
#pragma unroll
        for (int mf = 0; mf < 2; ++mf) {
            f16x8 a;
#pragma unroll
            for (int jt = 0; jt < 4; ++jt) {
                const int t = (mf * 32 + q * 8 + jt * 2) >> 1;
                const int idx = (t < 27) ? nbr[(size_t)t * Nout + site] : Nout;
                const f16x2 f = *(const f16x2*)(F16 + (size_t)idx * 2);
                a[jt * 2] = f.x; a[jt * 2 + 1] = f.y;
            }
            acc = __builtin_amdgcn_mfma_f32_16x16x32_f16(a, mf ? b1 : b0, acc, 0, 0, 0);
        }
#pragma unroll
        for (int r = 0; r < 4; ++r) {
            const int row = base + q * 4 + r;
            const float v = acc[r];
            if (row < Nout) {
                out[(size_t)row * 16 + l15] = v;
                s += v; ss += v * v;
            }
        }
    }

    s  += __shfl_xor(s, 16);  s  += __shfl_xor(s, 32);
    ss += __shfl_xor(ss, 16); ss += __shfl_xor(ss, 32);
    __shared__ float red[4][32];
    if (lane < 16) { red[wave][l15] = s; red[wave][16 + l15] = ss; }
    __syncthreads();
    if (threadIdx.x < 32) {
        const int t2 = threadIdx.x;
        float* bank = stats_out + (blockIdx.x & (NREP - 1)) * 128;
        atomicAdd(bank + (t2 < 16 ? t2 : 48 + t2),
                  red[0][t2] + red[1][t2] + red[2][t2] + red[3][t2]);
    }
}

// ---------------------------------------------------------------------------
// Pack fp32 weights into per-lane fp16 B fragments. blockIdx: 0 = p1,
// 1..6 = {w1,w2} x 3 levels (K=27, 14 pairs), 7..8 = dw (K=8, 4 pairs).
__global__ void pack_k(const float* __restrict__ w_p1, const float* __restrict__ w1,
                       const float* __restrict__ w2, const float* __restrict__ dw,
                       _Float16* __restrict__ WBp1, _Float16* __restrict__ WB27,
                       _Float16* __restrict__ WB8)
{
    const int b = blockIdx.x;
    if (b == 0) {
        for (int v = threadIdx.x; v < 2 * 64 * 8; v += 256) {
            const int mf = v >> 9, lane = (v >> 3) & 63, j = v & 7;
            const int qq = lane >> 4, n = lane & 15;
            const int kg = mf * 32 + qq * 8 + j;
            const int t = kg >> 1, cin = kg & 1;
            WBp1[v] = (t < 27) ? (_Float16)w_p1[t * 32 + cin * 16 + n] : (_Float16)0.f;
        }
    } else if (b <= 6) {
        const int ti = b - 1, lvl = ti >> 1;
        const float* src = ((ti & 1) ? w2 : w1) + lvl * 6912;
        _Float16* dst = WB27 + (size_t)ti * (14 * 64 * 8);
        for (int v = threadIdx.x; v < 14 * 64 * 8; v += 256) {
            const int p = v >> 9, lane = (v >> 3) & 63, j = v & 7;
            const int qq = lane >> 4, n = lane & 15;
            const int t = 2 * p + (qq >> 1);
            const int cin = (qq & 1) * 8 + j;
            dst[v] = (t < 27) ? (_Float16)src[t * 256 + cin * 16 + n] : (_Float16)0.f;
        }
    } else {
        const int ti = b - 7;
        const float* src = dw + ti * 2048;
        _Float16* dst = WB8 + (size_t)ti * (4 * 64 * 8);
        for (int v = threadIdx.x; v < 4 * 64 * 8; v += 256) {
            const int p = v >> 9, lane = (v >> 3) & 63, j = v & 7;
            const int qq = lane >> 4, n = lane & 15;
            const int t = 2 * p + (qq >> 1);
            const int cin = (qq & 1) * 8 + j;
            dst[v] = (_Float16)src[t * 256 + cin * 16 + n];
        }
    }
}

// ---------------------------------------------------------------------------
// BN+ReLU apply -> fp16 activations (incl. zero row at n == N).
// Sums the NREP stats replica banks in-thread.
__global__ __launch_bounds__(256) void apply16_k(
    const float* __restrict__ x, const float* __restrict__ stats,
    const float* __restrict__ g, const float* __restrict__ b,
    _Float16* __restrict__ A16, int N, float invN)
{
    const int t = blockIdx.x * 256 + threadIdx.x;
    if (t >= (N + 1) * 4) return;
    const int n = t >> 2, c = (t & 3) * 4;
    f16x4 r;
    if (n == N) {
        r[0] = r[1] = r[2] = r[3] = (_Float16)0.f;
    } else {
        const float4 v = *(const float4*)(x + (size_t)n * 16 + c);
        float vv[4] = {v.x, v.y, v.z, v.w};
#pragma unroll
        for (int i = 0; i < 4; ++i) {
            float su = 0.f, sq = 0.f;
#pragma unroll
            for (int rep = 0; rep < NREP; ++rep) {
                su += stats[rep * 128 + c + i];
                sq += stats[rep * 128 + 64 + c + i];
            }
            const float mean = su * invN;
            const float var  = sq * invN - mean * mean;
            const float sc   = g[c + i] * rsqrtf(var + BN_EPS);
            const float bi   = fmaf(-mean, sc, b[c + i]);
            r[i] = (_Float16)fmaxf(fmaf(vv[i], sc, bi), 0.f);
        }
    }
    *(f16x4*)(A16 + (size_t)n * 16 + c) = r;
}

// ---------------------------------------------------------------------------
// feats (fp32 [N0,2]) -> fp16 [N0+1,2] with zero row at N0.
__global__ void f16cvt_k(const float* __restrict__ f, _Float16* __restrict__ F16, int N)
{
    const int t = blockIdx.x * 256 + threadIdx.x;
    if (t > N) return;
    f16x2 r;
    if (t == N) { r[0] = r[1] = (_Float16)0.f; }
    else { const float2 v = *(const float2*)(f + (size_t)t * 2); r[0] = (_Float16)v.x; r[1] = (_Float16)v.y; }
    *(f16x2*)(F16 + (size_t)t * 2) = r;
}

// ---------------------------------------------------------------------------
// BN finalize for the final 48-ch BN (sums NREP replicas).
__global__ void fin_k(float* __restrict__ stats, const float* __restrict__ g,
                      const float* __restrict__ b, float* __restrict__ sb,
                      int C, float invN)
{
    const int c = threadIdx.x;
    if (c < C) {
        float su = 0.f, sq = 0.f;
#pragma unroll
        for (int rep = 0; rep < NREP; ++rep) {
            su += stats[rep * 128 + c];
            sq += stats[rep * 128 + 64 + c];
        }
        const float mean = su * invN;
        const float var = sq * invN - mean * mean;
        const float s = g[c] * rsqrtf(var + BN_EPS);
        sb[c] = s;
        sb[64 + c] = fmaf(-mean, s, b[c]);
    }
}

// ---------------------------------------------------------------------------
__device__ __forceinline__ float wred(float v) {
#pragma unroll
    for (int off = 32; off > 0; off >>= 1) v += __shfl_xor(v, off);
    return v;
}

// Stats of the gathered concat [r0 | r1[p01] | r2[p12[p01]]] over N0 rows.
__global__ __launch_bounds__(256) void gstats_k(
    const float* __restrict__ R0, const float* __restrict__ R1,
    const float* __restrict__ R2, const int* __restrict__ p01,
    const int* __restrict__ p12, float* __restrict__ stats, int N0)
{
    float s[48], q[48];
#pragma unroll
    for (int c = 0; c < 48; ++c) { s[c] = 0.f; q[c] = 0.f; }

    for (int n = blockIdx.x * blockDim.x + threadIdx.x; n < N0;
         n += gridDim.x * blockDim.x) {
        const int i1 = p01[n];
        const int i2 = p12[i1];
        const float4* a0 = (const float4*)(R0 + (size_t)n * 16);
        const float4* a1 = (const float4*)(R1 + (size_t)i1 * 16);
        const float4* a2 = (const float4*)(R2 + (size_t)i2 * 16);
#pragma unroll
        for (int j = 0; j < 4; ++j) {
            const float4 v = a0[j]; const int c = 4 * j;
            s[c] += v.x; q[c] += v.x * v.x; s[c+1] += v.y; q[c+1] += v.y * v.y;
            s[c+2] += v.z; q[c+2] += v.z * v.z; s[c+3] += v.w; q[c+3] += v.w * v.w;
        }
#pragma unroll
        for (int j = 0; j < 4; ++j) {
            const float4 v = a1[j]; const int c = 16 + 4 * j;
            s[c] += v.x; q[c] += v.x * v.x; s[c+1] += v.y; q[c+1] += v.y * v.y;
            s[c+2] += v.z; q[c+2] += v.z * v.z; s[c+3] += v.w; q[c+3] += v.w * v.w;
        }
#pragma unroll
        for (int j = 0; j < 4; ++j) {
            const float4 v = a2[j]; const int c = 32 + 4 * j;
            s[c] += v.x; q[c] += v.x * v.x; s[c+1] += v.y; q[c+1] += v.y * v.y;
            s[c+2] += v.z; q[c+2] += v.z * v.z; s[c+3] += v.w; q[c+3] += v.w * v.w;
        }
    }

    __shared__ float red[4][96];
    const int wave = threadIdx.x >> 6, lane = threadIdx.x & 63;
#pragma unroll
    for (int c = 0; c < 48; ++c) {
        const float ss = wred(s[c]);
        const float qq = wred(q[c]);
        if (lane == 0) { red[wave][c] = ss; red[wave][48 + c] = qq; }
    }
    __syncthreads();
    const int t = threadIdx.x;
    if (t < 96) {
        float* bank = stats + (blockIdx.x & (NREP - 1)) * 128;
        const float v = red[0][t] + red[1][t] + red[2][t] + red[3][t];
        atomicAdd(bank + (t < 48 ? t : 64 + (t - 48)), v);
    }
}

// ---------------------------------------------------------------------------
// Final: out[n] = relu(bn48(concat)) . w_sdf + b_sdf
__global__ __launch_bounds__(256) void out_k(
    const float* __restrict__ R0, const float* __restrict__ R1,
    const float* __restrict__ R2, const int* __restrict__ p01,
    const int* __restrict__ p12, const float* __restrict__ sb,
    const float* __restrict__ wsdf, const float* __restrict__ bsdf,
    float* __restrict__ out, int N0)
{
    const int n = blockIdx.x * 256 + threadIdx.x;
    if (n >= N0) return;
    const int i1 = p01[n];
    const int i2 = p12[i1];
    float acc = bsdf[0];
    const float4* a0 = (const float4*)(R0 + (size_t)n * 16);
    const float4* a1 = (const float4*)(R1 + (size_t)i1 * 16);
    const float4* a2 = (const float4*)(R2 + (size_t)i2 * 16);
#pragma unroll
    for (int j = 0; j < 4; ++j) {
        const float4 v = a0[j]; const int c = 4 * j;
        acc += fmaxf(fmaf(v.x, sb[c+0], sb[64+c+0]), 0.f) * wsdf[c+0];
        acc += fmaxf(fmaf(v.y, sb[c+1], sb[64+c+1]), 0.f) * wsdf[c+1];
        acc += fmaxf(fmaf(v.z, sb[c+2], sb[64+c+2]), 0.f) * wsdf[c+2];
        acc += fmaxf(fmaf(v.w, sb[c+3], sb[64+c+3]), 0.f) * wsdf[c+3];
    }
#pragma unroll
    for (int j = 0; j < 4; ++j) {
        const float4 v = a1[j]; const int c = 16 + 4 * j;
        acc += fmaxf(fmaf(v.x, sb[c+0], sb[64+c+0]), 0.f) * wsdf[c+0];
        acc += fmaxf(fmaf(v.y, sb[c+1], sb[64+c+1]), 0.f) * wsdf[c+1];
        acc += fmaxf(fmaf(v.z, sb[c+2], sb[64+c+2]), 0.f) * wsdf[c+2];
        acc += fmaxf(fmaf(v.w, sb[c+3], sb[64+c+3]), 0.f) * wsdf[c+3];
    }
#pragma unroll
    for (int j = 0; j < 4; ++j) {
        const float4 v = a2[j]; const int c = 32 + 4 * j;
        acc += fmaxf(fmaf(v.x, sb[c+0], sb[64+c+0]), 0.f) * wsdf[c+0];
        acc += fmaxf(fmaf(v.y, sb[c+1], sb[64+c+1]), 0.f) * wsdf[c+1];
        acc += fmaxf(fmaf(v.z, sb[c+2], sb[64+c+2]), 0.f) * wsdf[c+2];
        acc += fmaxf(fmaf(v.w, sb[c+3], sb[64+c+3]), 0.f) * wsdf[c+3];
    }
    out[n] = acc;
}

// ---------------------------------------------------------------------------
extern "C" void kernel_launch(void* const* d_in, const int* in_sizes, int n_in,
                              void* d_out, int out_size, void* d_ws, size_t ws_size,
                              hipStream_t stream)
{
    const float* feats = (const float*)d_in[0];
    const float* w_p1  = (const float*)d_in[1];
    const float* bn1g  = (const float*)d_in[2];
    const float* bn1b  = (const float*)d_in[3];
    const float* w1    = (const float*)d_in[4];
    const float* bn2g  = (const float*)d_in[5];
    const float* bn2b  = (const float*)d_in[6];
    const float* w2    = (const float*)d_in[7];
    const float* dbng  = (const float*)d_in[8];
    const float* dbnb  = (const float*)d_in[9];
    const float* dw    = (const float*)d_in[10];
    const float* bn3g  = (const float*)d_in[11];
    const float* bn3b  = (const float*)d_in[12];
    const float* wsdf  = (const float*)d_in[13];
    const float* bsdf  = (const float*)d_in[14];
    const int* nbr0    = (const int*)d_in[15];
    const int* nbr1    = (const int*)d_in[16];
    const int* nbr2    = (const int*)d_in[17];
    const int* down01  = (const int*)d_in[18];
    const int* down12  = (const int*)d_in[19];
    const int* p01     = (const int*)d_in[20];
    const int* p12     = (const int*)d_in[21];

    const int N0 = in_sizes[0] / 2;
    const int N1 = in_sizes[18] / 8;
    const int N2 = in_sizes[19] / 8;

    // workspace carve-up (256B aligned segments)
    char* wp = (char*)d_ws;
    auto alloc = [&](size_t bytes) { char* r = wp; wp += (bytes + 255) & ~(size_t)255; return r; };
    float* T  = (float*)alloc((size_t)N0 * 16 * 4);
    float* R0 = (float*)alloc((size_t)N0 * 16 * 4);
    float* R1 = (float*)alloc((size_t)N1 * 16 * 4);
    float* R2 = (float*)alloc((size_t)N2 * 16 * 4);
    float* st = (float*)alloc(9 * NREP * 128 * 4);
    float* sb = (float*)alloc(128 * 4);
    _Float16* A16  = (_Float16*)alloc((size_t)(N0 + 1) * 16 * 2);
    _Float16* F16  = (_Float16*)alloc((size_t)(N0 + 1) * 2 * 2);
    _Float16* WBp1 = (_Float16*)alloc(2 * 64 * 8 * 2);
    _Float16* WB27 = (_Float16*)alloc(6 * 14 * 64 * 8 * 2);
    _Float16* WB8  = (_Float16*)alloc(2 * 4 * 64 * 8 * 2);

    hipMemsetAsync(st, 0, 9 * NREP * 128 * sizeof(float), stream);

    const dim3 B(256);
    auto cgrid = [](int n) {  // persistent conv grid: <=2048 blocks, 4 waves each
        const int g = (((n + 15) / 16) + 3) / 4;
        return dim3((unsigned)(g < 2048 ? g : 2048));
    };
    auto agrid = [](int n) { return dim3((unsigned)(((n + 1) * 4 + 255) / 256)); };
    const float i0 = 1.0f / N0, i1 = 1.0f / N1, i2 = 1.0f / N2;
    auto S = [&](int i) { return st + i * NREP * 128; };
    auto W27 = [&](int i) { return WB27 + (size_t)i * (14 * 64 * 8); };
    auto W8  = [&](int i) { return WB8 + (size_t)i * (4 * 64 * 8); };

    pack_k<<<9, B, 0, stream>>>(w_p1, w1, w2, dw, WBp1, WB27, WB8);
    f16cvt_k<<<dim3((unsigned)((N0 + 256) / 256)), B, 0, stream>>>(feats, F16, N0);

    // ---- level 0 ----
    convp1_k<<<cgrid(N0), B, 0, stream>>>(F16, nbr0, WBp1, R0, S(0), N0);
    apply16_k<<<agrid(N0), B, 0, stream>>>(R0, S(0), bn1g, bn1b, A16, N0, i0);
    conv16_k<27><<<cgrid(N0), B, 0, stream>>>(A16, nbr0, W27(0), T, S(1), N0, 0);
    apply16_k<<<agrid(N0), B, 0, stream>>>(T, S(1), bn2g, bn2b, A16, N0, i0);
    conv16_k<27><<<cgrid(N0), B, 0, stream>>>(A16, nbr0, W27(1), R0, S(2), N0, 1);
    apply16_k<<<agrid(N0), B, 0, stream>>>(R0, S(2), dbng, dbnb, A16, N0, i0);
    conv16_k<8><<<cgrid(N1), B, 0, stream>>>(A16, down01, W8(0), R1, S(3), N1, 0);

    // ---- level 1 ----
    apply16_k<<<agrid(N1), B, 0, stream>>>(R1, S(3), bn1g + 16, bn1b + 16, A16, N1, i1);
    conv16_k<27><<<cgrid(N1), B, 0, stream>>>(A16, nbr1, W27(2), T, S(4), N1, 0);
    apply16_k<<<agrid(N1), B, 0, stream>>>(T, S(4), bn2g + 16, bn2b + 16, A16, N1, i1);
    conv16_k<27><<<cgrid(N1), B, 0, stream>>>(A16, nbr1, W27(3), R1, S(5), N1, 1);
    apply16_k<<<agrid(N1), B, 0, stream>>>(R1, S(5), dbng + 16, dbnb + 16, A16, N1, i1);
    conv16_k<8><<<cgrid(N2), B, 0, stream>>>(A16, down12, W8(1), R2, S(6), N2, 0);

    // ---- level 2 ----
    apply16_k<<<agrid(N2), B, 0, stream>>>(R2, S(6), bn1g + 32, bn1b + 32, A16, N2, i2);
    conv16_k<27><<<cgrid(N2), B, 0, stream>>>(A16, nbr2, W27(4), T, S(7), N2, 0);
    apply16_k<<<agrid(N2), B, 0, stream>>>(T, S(7), bn2g + 32, bn2b + 32, A16, N2, i2);
    conv16_k<27><<<cgrid(N2), B, 0, stream>>>(A16, nbr2, W27(5), R2, nullptr, N2, 1);

    // ---- final concat + BN48 + ReLU + linear ----
    gstats_k<<<512, B, 0, stream>>>(R0, R1, R2, p01, p12, S(8), N0);
    fin_k<<<1, 64, 0, stream>>>(S(8), bn3g, bn3b, sb, 48, i0);
    out_k<<<dim3((unsigned)((N0 + 255) / 256)), B, 0, stream>>>(
        R0, R1, R2, p01, p12, sb, wsdf, bsdf, (float*)d_out, N0);
}

// Round 6
// 789.117 us; speedup vs baseline: 1.0558x; 1.0558x over previous
//
#include <hip/hip_runtime.h>

#define BN_EPS 1e-4f
#define NREP 8   // stats replica banks (atomic-contention spreading)

typedef _Float16 f16x8 __attribute__((ext_vector_type(8)));
typedef _Float16 f16x4 __attribute__((ext_vector_type(4)));
typedef _Float16 f16x2 __attribute__((ext_vector_type(2)));
typedef float f32x4 __attribute__((ext_vector_type(4)));

// ---------------------------------------------------------------------------
// Transpose rulebook [K][N] -> [N][32], taps 27..31 padded with sentinel Nin.
// Reads coalesced per tap; writes 8 int4 per site.
__global__ __launch_bounds__(256) void tr_k(const int* __restrict__ nbr,
                                            int* __restrict__ nbrT,
                                            int N, int Nin)
{
    const int i = blockIdx.x * 256 + threadIdx.x;
    if (i >= N) return;
    int v[32];
#pragma unroll
    for (int k = 0; k < 27; ++k) v[k] = nbr[(size_t)k * N + i];
#pragma unroll
    for (int k = 27; k < 32; ++k) v[k] = Nin;
    int4* dst = (int4*)(nbrT + (size_t)i * 32);
#pragma unroll
    for (int j = 0; j < 8; ++j)
        dst[j] = make_int4(v[4 * j], v[4 * j + 1], v[4 * j + 2], v[4 * j + 3]);
}

// ---------------------------------------------------------------------------
// MFMA rulebook conv, CIN=16, K=27, transposed rulebook + LDS idx staging.
// Per 16-site group:
//   - 2 coalesced dwordx4 loads fetch all 27(32) taps x 16 sites of idx
//     (was 14 dword loads) -> staged via LDS (LDS unit, not TA)
//   - gathers are EXEC-MASKED: sentinel lanes issue no memory request
//   - all-sentinel tap-pairs skip gather+MFMA entirely (__any ballot)
// BN stats in registers across the group loop; one atomic set per block.
__global__ __launch_bounds__(256, 4) void conv16t_k(
    const _Float16* __restrict__ A16,   // [Nin+1, 16] post-BN fp16
    const int* __restrict__ nbrT,       // [Nin_out..][32] transposed, sentinel Nin
    const _Float16* __restrict__ WB,    // [14][64][8] packed B fragments
    float* __restrict__ out,            // [Nout, 16] fp32
    float* __restrict__ stats_out,      // [NREP][128] (sum | sumsq@64) or nullptr
    int Nout, int Nin, int addSkip)
{
    constexpr int K = 27, PAIRS = 14;
    __shared__ int lds[4][16 * 36];     // per-wave [site][36] (pad vs bank conflicts)
    const int wave = threadIdx.x >> 6, lane = threadIdx.x & 63;
    const int l15 = lane & 15, q = lane >> 4;
    const int h = q & 1;        // cin half
    const int th = q >> 1;      // tap-of-pair select
    int* L = lds[wave];

    f16x8 bfr[PAIRS];
#pragma unroll
    for (int p = 0; p < PAIRS; ++p)
        bfr[p] = *(const f16x8*)(WB + ((size_t)p * 64 + lane) * 8);

    const int ngroups = (Nout + 15) >> 4;
    float s = 0.f, ss = 0.f;

    for (int grp = blockIdx.x * 4 + wave; grp < ngroups; grp += gridDim.x * 4) {
        const int base = grp * 16;
        const int site = min(base + l15, Nout - 1);

        // stage idx tile: lane reads taps [q*4..q*4+3] and [16+q*4..] of site l15
        const int4* src = (const int4*)(nbrT + (size_t)site * 32);
        const int4 c0 = src[q];
        const int4 c1 = src[q + 4];
        *(int4*)(L + l15 * 36 + q * 4) = c0;
        *(int4*)(L + l15 * 36 + 16 + q * 4) = c1;

        int idxs[PAIRS];
#pragma unroll
        for (int p = 0; p < PAIRS; ++p) {
            const int t = 2 * p + ((2 * p + 1 < K) ? th : 0);  // odd-K: dup tap 26
            idxs[p] = L[l15 * 36 + t];
        }

        f32x4 acc0 = {0.f, 0.f, 0.f, 0.f}, acc1 = {0.f, 0.f, 0.f, 0.f};
#pragma unroll
        for (int p = 0; p < PAIRS; ++p) {
            const int idx = idxs[p];
            if (__any(idx < Nin)) {          // wave-uniform pair skip
                f16x8 a = {};
                if (idx < Nin)               // exec-masked gather
                    a = *(const f16x8*)(A16 + (size_t)idx * 16 + h * 8);
                if (p & 1) acc1 = __builtin_amdgcn_mfma_f32_16x16x32_f16(a, bfr[p], acc1, 0, 0, 0);
                else       acc0 = __builtin_amdgcn_mfma_f32_16x16x32_f16(a, bfr[p], acc0, 0, 0, 0);
            }
        }

#pragma unroll
        for (int r = 0; r < 4; ++r) {
            const int row = base + q * 4 + r;
            float v = acc0[r] + acc1[r];
            if (row < Nout) {
                float* op = out + (size_t)row * 16 + l15;
                if (addSkip) v += *op;
                *op = v;
                s += v; ss += v * v;
            }
        }
    }

    if (stats_out) {
        s  += __shfl_xor(s, 16);  s  += __shfl_xor(s, 32);
        ss += __shfl_xor(ss, 16); ss += __shfl_xor(ss, 32);
        __shared__ float red[4][32];
        if (lane < 16) { red[wave][l15] = s; red[wave][16 + l15] = ss; }
        __syncthreads();
        if (threadIdx.x < 32) {
            const int t2 = threadIdx.x;
            float* bank = stats_out + (blockIdx.x & (NREP - 1)) * 128;
            atomicAdd(bank + (t2 < 16 ? t2 : 48 + t2),
                      red[0][t2] + red[1][t2] + red[2][t2] + red[3][t2]);
        }
    }
}

// ---------------------------------------------------------------------------
// Dense-rulebook conv (K=8 down-convs): unchanged structure + masked gathers.
template <int K>
__global__ __launch_bounds__(256, 4) void conv16_k(
    const _Float16* __restrict__ A16, const int* __restrict__ nbr,
    const _Float16* __restrict__ WB, float* __restrict__ out,
    float* __restrict__ stats_out, int Nout, int Nin, int addSkip)
{
    constexpr int PAIRS = (K + 1) / 2;
    const int wave = threadIdx.x >> 6, lane = threadIdx.x & 63;
    const int l15 = lane & 15, q = lane >> 4;
    const int h = q & 1, th = q >> 1;

    f16x8 bfr[PAIRS];
#pragma unroll
    for (int p = 0; p < PAIRS; ++p)
        bfr[p] = *(const f16x8*)(WB + ((size_t)p * 64 + lane) * 8);

    const int ngroups = (Nout + 15) >> 4;
    float s = 0.f, ss = 0.f;

    for (int grp = blockIdx.x * 4 + wave; grp < ngroups; grp += gridDim.x * 4) {
        const int base = grp * 16;
        const int site = min(base + l15, Nout - 1);
        f32x4 acc0 = {0.f, 0.f, 0.f, 0.f}, acc1 = {0.f, 0.f, 0.f, 0.f};
#pragma unroll
        for (int p = 0; p < PAIRS; ++p) {
            const int t = 2 * p + ((2 * p + 1 < K) ? th : 0);
            const int idx = nbr[(size_t)t * Nout + site];
            f16x8 a = {};
            if (idx < Nin)
                a = *(const f16x8*)(A16 + (size_t)idx * 16 + h * 8);
            if (p & 1) acc1 = __builtin_amdgcn_mfma_f32_16x16x32_f16(a, bfr[p], acc1, 0, 0, 0);
            else       acc0 = __builtin_amdgcn_mfma_f32_16x16x32_f16(a, bfr[p], acc0, 0, 0, 0);
        }
#pragma unroll
        for (int r = 0; r < 4; ++r) {
            const int row = base + q * 4 + r;
            float v = acc0[r] + acc1[r];
            if (row < Nout) {
                float* op = out + (size_t)row * 16 + l15;
                if (addSkip) v += *op;
                *op = v;
                s += v; ss += v * v;
            }
        }
    }

    if (stats_out) {
        s  += __shfl_xor(s, 16);  s  += __shfl_xor(s, 32);
        ss += __shfl_xor(ss, 16); ss += __shfl_xor(ss, 32);
        __shared__ float red[4][32];
        if (lane < 16) { red[wave][l15] = s; red[wave][16 + l15] = ss; }
        __syncthreads();
        if (threadIdx.x < 32) {
            const int t2 = threadIdx.x;
            float* bank = stats_out + (blockIdx.x & (NREP - 1)) * 128;
            atomicAdd(bank + (t2 < 16 ? t2 : 48 + t2),
                      red[0][t2] + red[1][t2] + red[2][t2] + red[3][t2]);
        }
    }
}

// ---------------------------------------------------------------------------
// p1 conv (CIN=2), transposed rulebook + LDS idx staging, masked f16x2 gathers.
// K-packing k = tap*2 + cin; lane needs taps {mf*16 + q*4 + jt}.
__global__ __launch_bounds__(256, 4) void convp1t_k(
    const _Float16* __restrict__ F16,   // [N0+1, 2]
    const int* __restrict__ nbrT,       // [N0][32] transposed, sentinel N0
    const _Float16* __restrict__ WB,    // [2][64][8]
    float* __restrict__ out, float* __restrict__ stats_out, int Nout)
{
    __shared__ int lds[4][16 * 36];
    const int wave = threadIdx.x >> 6, lane = threadIdx.x & 63;
    const int l15 = lane & 15, q = lane >> 4;
    int* L = lds[wave];

    f16x8 b0 = *(const f16x8*)(WB + (size_t)lane * 8);
    f16x8 b1 = *(const f16x8*)(WB + ((size_t)64 + lane) * 8);

    const int ngroups = (Nout + 15) >> 4;
    float s = 0.f, ss = 0.f;

    for (int grp = blockIdx.x * 4 + wave; grp < ngroups; grp += gridDim.x * 4) {
        const int base = grp * 16;
        const int site = min(base + l15, Nout - 1);

        const int4* src = (const int4*)(nbrT + (size_t)site * 32);
        const int4 c0 = src[q];
        const int4 c1 = src[q + 4];
        *(int4*)(L + l15 * 36 + q * 4) = c0;
        *(int4*)(L + l15 * 36 + 16 + q * 4) = c1;

        f32x4 acc = {0.f, 0.f, 0.f, 0.f};
#pragma unroll
        for (int mf = 0; mf < 2; ++mf) {
            int tid[4];
#pragma unroll
            for (int jt = 0; jt < 4; ++jt)
                tid[jt] = L[l15 * 36 + mf * 16 + q * 4 + jt];
            f16x8 a;
#pragma unroll
            for (int jt = 0; jt < 4; ++jt) {
                const int idx = tid[jt];
                f16x2 f = {};
                if (idx < Nout)                 // pads are sentinel == N0
                    f = *(const f16x2*)(F16 + (size_t)idx * 2);
                a[jt * 2] = f.x; a[jt * 2 + 1] = f.y;
            }
            acc = __builtin_amdgcn_mfma_f32_16x16x32_f16(a, mf ? b1 : b0, acc, 0, 0, 0);
        }
#pragma unroll
        for (int r = 0; r < 4; ++r) {
            const int row = base + q * 4 + r;
            const float v = acc[r];
            if (row < Nout) {
                out[(size_t)row * 16 + l15] = v;
                s += v; ss += v * v;
            }
        }
    }

    s  += __shfl_xor(s, 16);  s  += __shfl_xor(s, 32);
    ss += __shfl_xor(ss, 16); ss += __shfl_xor(ss, 32);
    __shared__ float red[4][32];
    if (lane < 16) { red[wave][l15] = s; red[wave][16 + l15] = ss; }
    __syncthreads();
    if (threadIdx.x < 32) {
        const int t2 = threadIdx.x;
        float* bank = stats_out + (blockIdx.x & (NREP - 1)) * 128;
        atomicAdd(bank + (t2 < 16 ? t2 : 48 + t2),
                  red[0][t2] + red[1][t2] + red[2][t2] + red[3][t2]);
    }
}

// ---------------------------------------------------------------------------
// Pack fp32 weights into per-lane fp16 B fragments. blockIdx: 0 = p1,
// 1..6 = {w1,w2} x 3 levels (K=27, 14 pairs), 7..8 = dw (K=8, 4 pairs).
__global__ void pack_k(const float* __restrict__ w_p1, const float* __restrict__ w1,
                       const float* __restrict__ w2, const float* __restrict__ dw,
                       _Float16* __restrict__ WBp1, _Float16* __restrict__ WB27,
                       _Float16* __restrict__ WB8)
{
    const int b = blockIdx.x;
    if (b == 0) {
        for (int v = threadIdx.x; v < 2 * 64 * 8; v += 256) {
            const int mf = v >> 9, lane = (v >> 3) & 63, j = v & 7;
            const int qq = lane >> 4, n = lane & 15;
            const int kg = mf * 32 + qq * 8 + j;
            const int t = kg >> 1, cin = kg & 1;
            WBp1[v] = (t < 27) ? (_Float16)w_p1[t * 32 + cin * 16 + n] : (_Float16)0.f;
        }
    } else if (b <= 6) {
        const int ti = b - 1, lvl = ti >> 1;
        const float* src = ((ti & 1) ? w2 : w1) + lvl * 6912;
        _Float16* dst = WB27 + (size_t)ti * (14 * 64 * 8);
        for (int v = threadIdx.x; v < 14 * 64 * 8; v += 256) {
            const int p = v >> 9, lane = (v >> 3) & 63, j = v & 7;
            const int qq = lane >> 4, n = lane & 15;
            const int t = 2 * p + (qq >> 1);
            const int cin = (qq & 1) * 8 + j;
            dst[v] = (t < 27) ? (_Float16)src[t * 256 + cin * 16 + n] : (_Float16)0.f;
        }
    } else {
        const int ti = b - 7;
        const float* src = dw + ti * 2048;
        _Float16* dst = WB8 + (size_t)ti * (4 * 64 * 8);
        for (int v = threadIdx.x; v < 4 * 64 * 8; v += 256) {
            const int p = v >> 9, lane = (v >> 3) & 63, j = v & 7;
            const int qq = lane >> 4, n = lane & 15;
            const int t = 2 * p + (qq >> 1);
            const int cin = (qq & 1) * 8 + j;
            dst[v] = (_Float16)src[t * 256 + cin * 16 + n];
        }
    }
}

// ---------------------------------------------------------------------------
// BN+ReLU apply -> fp16 activations (incl. zero row at n == N).
__global__ __launch_bounds__(256) void apply16_k(
    const float* __restrict__ x, const float* __restrict__ stats,
    const float* __restrict__ g, const float* __restrict__ b,
    _Float16* __restrict__ A16, int N, float invN)
{
    const int t = blockIdx.x * 256 + threadIdx.x;
    if (t >= (N + 1) * 4) return;
    const int n = t >> 2, c = (t & 3) * 4;
    f16x4 r;
    if (n == N) {
        r[0] = r[1] = r[2] = r[3] = (_Float16)0.f;
    } else {
        const float4 v = *(const float4*)(x + (size_t)n * 16 + c);
        float vv[4] = {v.x, v.y, v.z, v.w};
#pragma unroll
        for (int i = 0; i < 4; ++i) {
            float su = 0.f, sq = 0.f;
#pragma unroll
            for (int rep = 0; rep < NREP; ++rep) {
                su += stats[rep * 128 + c + i];
                sq += stats[rep * 128 + 64 + c + i];
            }
            const float mean = su * invN;
            const float var  = sq * invN - mean * mean;
            const float sc   = g[c + i] * rsqrtf(var + BN_EPS);
            const float bi   = fmaf(-mean, sc, b[c + i]);
            r[i] = (_Float16)fmaxf(fmaf(vv[i], sc, bi), 0.f);
        }
    }
    *(f16x4*)(A16 + (size_t)n * 16 + c) = r;
}

// ---------------------------------------------------------------------------
__global__ void f16cvt_k(const float* __restrict__ f, _Float16* __restrict__ F16, int N)
{
    const int t = blockIdx.x * 256 + threadIdx.x;
    if (t > N) return;
    f16x2 r;
    if (t == N) { r[0] = r[1] = (_Float16)0.f; }
    else { const float2 v = *(const float2*)(f + (size_t)t * 2); r[0] = (_Float16)v.x; r[1] = (_Float16)v.y; }
    *(f16x2*)(F16 + (size_t)t * 2) = r;
}

// ---------------------------------------------------------------------------
__global__ void fin_k(float* __restrict__ stats, const float* __restrict__ g,
                      const float* __restrict__ b, float* __restrict__ sb,
                      int C, float invN)
{
    const int c = threadIdx.x;
    if (c < C) {
        float su = 0.f, sq = 0.f;
#pragma unroll
        for (int rep = 0; rep < NREP; ++rep) {
            su += stats[rep * 128 + c];
            sq += stats[rep * 128 + 64 + c];
        }
        const float mean = su * invN;
        const float var = sq * invN - mean * mean;
        const float s = g[c] * rsqrtf(var + BN_EPS);
        sb[c] = s;
        sb[64 + c] = fmaf(-mean, s, b[c]);
    }
}

// ---------------------------------------------------------------------------
__device__ __forceinline__ float wred(float v) {
#pragma unroll
    for (int off = 32; off > 0; off >>= 1) v += __shfl_xor(v, off);
    return v;
}

__global__ __launch_bounds__(256) void gstats_k(
    const float* __restrict__ R0, const float* __restrict__ R1,
    const float* __restrict__ R2, const int* __restrict__ p01,
    const int* __restrict__ p12, float* __restrict__ stats, int N0)
{
    float s[48], q[48];
#pragma unroll
    for (int c = 0; c < 48; ++c) { s[c] = 0.f; q[c] = 0.f; }

    for (int n = blockIdx.x * blockDim.x + threadIdx.x; n < N0;
         n += gridDim.x * blockDim.x) {
        const int i1 = p01[n];
        const int i2 = p12[i1];
        const float4* a0 = (const float4*)(R0 + (size_t)n * 16);
        const float4* a1 = (const float4*)(R1 + (size_t)i1 * 16);
        const float4* a2 = (const float4*)(R2 + (size_t)i2 * 16);
#pragma unroll
        for (int j = 0; j < 4; ++j) {
            const float4 v = a0[j]; const int c = 4 * j;
            s[c] += v.x; q[c] += v.x * v.x; s[c+1] += v.y; q[c+1] += v.y * v.y;
            s[c+2] += v.z; q[c+2] += v.z * v.z; s[c+3] += v.w; q[c+3] += v.w * v.w;
        }
#pragma unroll
        for (int j = 0; j < 4; ++j) {
            const float4 v = a1[j]; const int c = 16 + 4 * j;
            s[c] += v.x; q[c] += v.x * v.x; s[c+1] += v.y; q[c+1] += v.y * v.y;
            s[c+2] += v.z; q[c+2] += v.z * v.z; s[c+3] += v.w; q[c+3] += v.w * v.w;
        }
#pragma unroll
        for (int j = 0; j < 4; ++j) {
            const float4 v = a2[j]; const int c = 32 + 4 * j;
            s[c] += v.x; q[c] += v.x * v.x; s[c+1] += v.y; q[c+1] += v.y * v.y;
            s[c+2] += v.z; q[c+2] += v.z * v.z; s[c+3] += v.w; q[c+3] += v.w * v.w;
        }
    }

    __shared__ float red[4][96];
    const int wave = threadIdx.x >> 6, lane = threadIdx.x & 63;
#pragma unroll
    for (int c = 0; c < 48; ++c) {
        const float ss = wred(s[c]);
        const float qq = wred(q[c]);
        if (lane == 0) { red[wave][c] = ss; red[wave][48 + c] = qq; }
    }
    __syncthreads();
    const int t = threadIdx.x;
    if (t < 96) {
        float* bank = stats + (blockIdx.x & (NREP - 1)) * 128;
        const float v = red[0][t] + red[1][t] + red[2][t] + red[3][t];
        atomicAdd(bank + (t < 48 ? t : 64 + (t - 48)), v);
    }
}

// ---------------------------------------------------------------------------
__global__ __launch_bounds__(256) void out_k(
    const float* __restrict__ R0, const float* __restrict__ R1,
    const float* __restrict__ R2, const int* __restrict__ p01,
    const int* __restrict__ p12, const float* __restrict__ sb,
    const float* __restrict__ wsdf, const float* __restrict__ bsdf,
    float* __restrict__ out, int N0)
{
    const int n = blockIdx.x * 256 + threadIdx.x;
    if (n >= N0) return;
    const int i1 = p01[n];
    const int i2 = p12[i1];
    float acc = bsdf[0];
    const float4* a0 = (const float4*)(R0 + (size_t)n * 16);
    const float4* a1 = (const float4*)(R1 + (size_t)i1 * 16);
    const float4* a2 = (const float4*)(R2 + (size_t)i2 * 16);
#pragma unroll
    for (int j = 0; j < 4; ++j) {
        const float4 v = a0[j]; const int c = 4 * j;
        acc += fmaxf(fmaf(v.x, sb[c+0], sb[64+c+0]), 0.f) * wsdf[c+0];
        acc += fmaxf(fmaf(v.y, sb[c+1], sb[64+c+1]), 0.f) * wsdf[c+1];
        acc += fmaxf(fmaf(v.z, sb[c+2], sb[64+c+2]), 0.f) * wsdf[c+2];
        acc += fmaxf(fmaf(v.w, sb[c+3], sb[64+c+3]), 0.f) * wsdf[c+3];
    }
#pragma unroll
    for (int j = 0; j < 4; ++j) {
        const float4 v = a1[j]; const int c = 16 + 4 * j;
        acc += fmaxf(fmaf(v.x, sb[c+0], sb[64+c+0]), 0.f) * wsdf[c+0];
        acc += fmaxf(fmaf(v.y, sb[c+1], sb[64+c+1]), 0.f) * wsdf[c+1];
        acc += fmaxf(fmaf(v.z, sb[c+2], sb[64+c+2]), 0.f) * wsdf[c+2];
        acc += fmaxf(fmaf(v.w, sb[c+3], sb[64+c+3]), 0.f) * wsdf[c+3];
    }
#pragma unroll
    for (int j = 0; j < 4; ++j) {
        const float4 v = a2[j]; const int c = 32 + 4 * j;
        acc += fmaxf(fmaf(v.x, sb[c+0], sb[64+c+0]), 0.f) * wsdf[c+0];
        acc += fmaxf(fmaf(v.y, sb[c+1], sb[64+c+1]), 0.f) * wsdf[c+1];
        acc += fmaxf(fmaf(v.z, sb[c+2], sb[64+c+2]), 0.f) * wsdf[c+2];
        acc += fmaxf(fmaf(v.w, sb[c+3], sb[64+c+3]), 0.f) * wsdf[c+3];
    }
    out[n] = acc;
}

// ---------------------------------------------------------------------------
extern "C" void kernel_launch(void* const* d_in, const int* in_sizes, int n_in,
                              void* d_out, int out_size, void* d_ws, size_t ws_size,
                              hipStream_t stream)
{
    const float* feats = (const float*)d_in[0];
    const float* w_p1  = (const float*)d_in[1];
    const float* bn1g  = (const float*)d_in[2];
    const float* bn1b  = (const float*)d_in[3];
    const float* w1    = (const float*)d_in[4];
    const float* bn2g  = (const float*)d_in[5];
    const float* bn2b  = (const float*)d_in[6];
    const float* w2    = (const float*)d_in[7];
    const float* dbng  = (const float*)d_in[8];
    const float* dbnb  = (const float*)d_in[9];
    const float* dw    = (const float*)d_in[10];
    const float* bn3g  = (const float*)d_in[11];
    const float* bn3b  = (const float*)d_in[12];
    const float* wsdf  = (const float*)d_in[13];
    const float* bsdf  = (const float*)d_in[14];
    const int* nbr0    = (const int*)d_in[15];
    const int* nbr1    = (const int*)d_in[16];
    const int* nbr2    = (const int*)d_in[17];
    const int* down01  = (const int*)d_in[18];
    const int* down12  = (const int*)d_in[19];
    const int* p01     = (const int*)d_in[20];
    const int* p12     = (const int*)d_in[21];

    const int N0 = in_sizes[0] / 2;
    const int N1 = in_sizes[18] / 8;
    const int N2 = in_sizes[19] / 8;

    // workspace carve-up (256B aligned segments)
    char* wp = (char*)d_ws;
    auto alloc = [&](size_t bytes) { char* r = wp; wp += (bytes + 255) & ~(size_t)255; return r; };
    float* T  = (float*)alloc((size_t)N0 * 16 * 4);
    float* R0 = (float*)alloc((size_t)N0 * 16 * 4);
    float* R1 = (float*)alloc((size_t)N1 * 16 * 4);
    float* R2 = (float*)alloc((size_t)N2 * 16 * 4);
    float* st = (float*)alloc(9 * NREP * 128 * 4);
    float* sb = (float*)alloc(128 * 4);
    _Float16* A16  = (_Float16*)alloc((size_t)(N0 + 1) * 16 * 2);
    _Float16* F16  = (_Float16*)alloc((size_t)(N0 + 1) * 2 * 2);
    _Float16* WBp1 = (_Float16*)alloc(2 * 64 * 8 * 2);
    _Float16* WB27 = (_Float16*)alloc(6 * 14 * 64 * 8 * 2);
    _Float16* WB8  = (_Float16*)alloc(2 * 4 * 64 * 8 * 2);
    int* nbrT = (int*)alloc((size_t)N0 * 32 * 4);   // reused per level

    hipMemsetAsync(st, 0, 9 * NREP * 128 * sizeof(float), stream);

    const dim3 B(256);
    auto cgrid = [](int n) {  // persistent conv grid: <=2048 blocks, 4 waves each
        const int g = (((n + 15) / 16) + 3) / 4;
        return dim3((unsigned)(g < 2048 ? g : 2048));
    };
    auto agrid = [](int n) { return dim3((unsigned)(((n + 1) * 4 + 255) / 256)); };
    auto lgrid = [](int n) { return dim3((unsigned)((n + 255) / 256)); };
    const float i0 = 1.0f / N0, i1 = 1.0f / N1, i2 = 1.0f / N2;
    auto S = [&](int i) { return st + i * NREP * 128; };
    auto W27 = [&](int i) { return WB27 + (size_t)i * (14 * 64 * 8); };
    auto W8  = [&](int i) { return WB8 + (size_t)i * (4 * 64 * 8); };

    pack_k<<<9, B, 0, stream>>>(w_p1, w1, w2, dw, WBp1, WB27, WB8);
    f16cvt_k<<<lgrid(N0 + 1), B, 0, stream>>>(feats, F16, N0);

    // ---- level 0 (nbrT <- nbr0 transposed) ----
    tr_k<<<lgrid(N0), B, 0, stream>>>(nbr0, nbrT, N0, N0);
    convp1t_k<<<cgrid(N0), B, 0, stream>>>(F16, nbrT, WBp1, R0, S(0), N0);
    apply16_k<<<agrid(N0), B, 0, stream>>>(R0, S(0), bn1g, bn1b, A16, N0, i0);
    conv16t_k<<<cgrid(N0), B, 0, stream>>>(A16, nbrT, W27(0), T, S(1), N0, N0, 0);
    apply16_k<<<agrid(N0), B, 0, stream>>>(T, S(1), bn2g, bn2b, A16, N0, i0);
    conv16t_k<<<cgrid(N0), B, 0, stream>>>(A16, nbrT, W27(1), R0, S(2), N0, N0, 1);
    apply16_k<<<agrid(N0), B, 0, stream>>>(R0, S(2), dbng, dbnb, A16, N0, i0);
    conv16_k<8><<<cgrid(N1), B, 0, stream>>>(A16, down01, W8(0), R1, S(3), N1, N0, 0);

    // ---- level 1 (nbrT <- nbr1 transposed; stream-ordered reuse) ----
    tr_k<<<lgrid(N1), B, 0, stream>>>(nbr1, nbrT, N1, N1);
    apply16_k<<<agrid(N1), B, 0, stream>>>(R1, S(3), bn1g + 16, bn1b + 16, A16, N1, i1);
    conv16t_k<<<cgrid(N1), B, 0, stream>>>(A16, nbrT, W27(2), T, S(4), N1, N1, 0);
    apply16_k<<<agrid(N1), B, 0, stream>>>(T, S(4), bn2g + 16, bn2b + 16, A16, N1, i1);
    conv16t_k<<<cgrid(N1), B, 0, stream>>>(A16, nbrT, W27(3), R1, S(5), N1, N1, 1);
    apply16_k<<<agrid(N1), B, 0, stream>>>(R1, S(5), dbng + 16, dbnb + 16, A16, N1, i1);
    conv16_k<8><<<cgrid(N2), B, 0, stream>>>(A16, down12, W8(1), R2, S(6), N2, N1, 0);

    // ---- level 2 ----
    tr_k<<<lgrid(N2), B, 0, stream>>>(nbr2, nbrT, N2, N2);
    apply16_k<<<agrid(N2), B, 0, stream>>>(R2, S(6), bn1g + 32, bn1b + 32, A16, N2, i2);
    conv16t_k<<<cgrid(N2), B, 0, stream>>>(A16, nbrT, W27(4), T, S(7), N2, N2, 0);
    apply16_k<<<agrid(N2), B, 0, stream>>>(T, S(7), bn2g + 32, bn2b + 32, A16, N2, i2);
    conv16t_k<<<cgrid(N2), B, 0, stream>>>(A16, nbrT, W27(5), R2, nullptr, N2, N2, 1);

    // ---- final concat + BN48 + ReLU + linear ----
    gstats_k<<<512, B, 0, stream>>>(R0, R1, R2, p01, p12, S(8), N0);
    fin_k<<<1, 64, 0, stream>>>(S(8), bn3g, bn3b, sb, 48, i0);
    out_k<<<lgrid(N0), B, 0, stream>>>(R0, R1, R2, p01, p12, sb, wsdf, bsdf,
                                       (float*)d_out, N0);
}